// Round 1
// baseline (903.122 us; speedup 1.0000x reference)
//
#include <hip/hip_runtime.h>

typedef _Float16 f16x8 __attribute__((ext_vector_type(8)));
typedef _Float16 f16x4 __attribute__((ext_vector_type(4)));
typedef float f32x4 __attribute__((ext_vector_type(4)));

#define NSEQ 2048
#define DMODEL 2048
#define NHEADS 32
#define NKV 8
#define DK 64

// ---------------- elementwise f32 -> f16 ----------------
__global__ void cvt_f32_f16(const float* __restrict__ in, _Float16* __restrict__ out, int n4) {
    int i = blockIdx.x * blockDim.x + threadIdx.x;
    int stride = gridDim.x * blockDim.x;
    for (; i < n4; i += stride) {
        float4 v = ((const float4*)in)[i];
        f16x4 h;
        h[0] = (_Float16)v.x; h[1] = (_Float16)v.y;
        h[2] = (_Float16)v.z; h[3] = (_Float16)v.w;
        ((f16x4*)out)[i] = h;
    }
}

// ---------------- transpose + convert: in f32 [R][C] -> out f16 [C][R] ----------------
__global__ __launch_bounds__(256) void transpose_cvt(const float* __restrict__ in,
                                                     _Float16* __restrict__ out,
                                                     int R, int C) {
    __shared__ float tile[32][33];
    int c0 = blockIdx.x * 32, r0 = blockIdx.y * 32;
    int tx = threadIdx.x, ty = threadIdx.y; // (32,8)
#pragma unroll
    for (int i = 0; i < 4; i++) {
        int r = r0 + ty + i * 8;
        tile[ty + i * 8][tx] = in[(long long)r * C + c0 + tx];
    }
    __syncthreads();
#pragma unroll
    for (int i = 0; i < 4; i++) {
        int c = c0 + ty + i * 8;
        out[(long long)c * R + r0 + tx] = (_Float16)tile[tx][ty + i * 8];
    }
}

// ---------------- RoPE cos/sin table: cs[n][j] = {cos(n*invf[j]), sin(n*invf[j])} ----------------
__global__ void rope_table(float2* __restrict__ cs) {
    int idx = blockIdx.x * blockDim.x + threadIdx.x; // 65536 total
    int n = idx >> 5, j = idx & 31;
    float e = (2.0f * j) / 64.0f;
    float invf = 1.0f / powf(10000.0f, e);
    float ang = (float)n * invf;
    float2 v; v.x = cosf(ang); v.y = sinf(ang);
    cs[idx] = v;
}

// ---------------- RoPE apply + f32->f16: per (n, head, j<32) pair ----------------
__global__ void rope_apply(const float* __restrict__ Qf, const float2* __restrict__ cs,
                           _Float16* __restrict__ Qh, int ncols) {
    int idx = blockIdx.x * blockDim.x + threadIdx.x;
    int halfrow = ncols >> 1;
    int n = idx / halfrow;
    int rem = idx - n * halfrow;
    int h = rem >> 5, j = rem & 31;
    float2 c = cs[n * 32 + j];
    long long base = (long long)n * ncols + h * 64;
    float x1 = Qf[base + j], x2 = Qf[base + j + 32];
    Qh[base + j]      = (_Float16)(x1 * c.x - x2 * c.y);
    Qh[base + j + 32] = (_Float16)(x2 * c.x + x1 * c.y);
}

// ---------------- GEMM: C[M,N] = alpha * A[M,K] @ Bt[N,K]^T  (fp16 MFMA, f32 accum) --------------
// A is f16 (ACVT=false) or f32 converted on the fly (ACVT=true). Bt is K-major f16.
// Per-z offsets: A += z*az, Bt += (z/bzdiv)*bz, C += z*cz.
template <int BM, int BN, int MF, int NF, bool ACVT>
__global__ __launch_bounds__(256) void gemm_bt(const void* __restrict__ Ap,
                                               const _Float16* __restrict__ Bt,
                                               float* __restrict__ C,
                                               int K, int lda, int ldb, int ldc,
                                               int az, int bz, int bzdiv, long long cz,
                                               float alpha) {
    constexpr int LDP = 56; // lds pitch in halfs: 112B -> 16B aligned rows, ~2-way banks
    __shared__ __align__(16) _Float16 As[BM][LDP];
    __shared__ __align__(16) _Float16 Bs[BN][LDP];

    const int tid = threadIdx.x;
    const int z = blockIdx.z;
    const int lane = tid & 63, wid = tid >> 6;
    constexpr int WC = BN / (NF * 16);
    const int wr = wid / WC, wc = wid % WC;
    const int wm = wr * MF * 16, wn = wc * NF * 16;
    const int am = lane & 15;
    const int k0 = (lane >> 4) * 8;

    f32x4 acc[MF][NF] = {};

    const long long a_row0 = (long long)blockIdx.y * BM * lda + (long long)z * az;
    const long long b_row0 = (long long)blockIdx.x * BN * ldb + (long long)(z / bzdiv) * bz;

    for (int kt = 0; kt < K; kt += 32) {
        if constexpr (!ACVT) {
            const _Float16* A = (const _Float16*)Ap + a_row0 + kt;
            for (int c = tid; c < BM * 4; c += 256) {
                int r = c >> 2, s = c & 3;
                *(f16x8*)&As[r][s * 8] = *(const f16x8*)(A + (long long)r * lda + s * 8);
            }
        } else {
            const float* A = (const float*)Ap + a_row0 + kt;
            for (int c = tid; c < BM * 8; c += 256) {
                int r = c >> 3, s = c & 7;
                float4 v = *(const float4*)(A + (long long)r * lda + s * 4);
                f16x4 h;
                h[0] = (_Float16)v.x; h[1] = (_Float16)v.y;
                h[2] = (_Float16)v.z; h[3] = (_Float16)v.w;
                *(f16x4*)&As[r][s * 4] = h;
            }
        }
        {
            const _Float16* B = Bt + b_row0 + kt;
            for (int c = tid; c < BN * 4; c += 256) {
                int r = c >> 2, s = c & 3;
                *(f16x8*)&Bs[r][s * 8] = *(const f16x8*)(B + (long long)r * ldb + s * 8);
            }
        }
        __syncthreads();

        f16x8 af[MF], bf[NF];
#pragma unroll
        for (int m = 0; m < MF; m++) af[m] = *(const f16x8*)&As[wm + m * 16 + am][k0];
#pragma unroll
        for (int n = 0; n < NF; n++) bf[n] = *(const f16x8*)&Bs[wn + n * 16 + am][k0];
#pragma unroll
        for (int m = 0; m < MF; m++)
#pragma unroll
            for (int n = 0; n < NF; n++)
                acc[m][n] = __builtin_amdgcn_mfma_f32_16x16x32_f16(af[m], bf[n], acc[m][n], 0, 0, 0);
        __syncthreads();
    }

    float* Cp = C + (long long)z * cz;
    const int rb = blockIdx.y * BM + wm + (lane >> 4) * 4;
    const int cb = blockIdx.x * BN + wn + am;
#pragma unroll
    for (int m = 0; m < MF; m++)
#pragma unroll
        for (int n = 0; n < NF; n++)
#pragma unroll
            for (int j = 0; j < 4; j++)
                Cp[(long long)(rb + m * 16 + j) * ldc + cb + n * 16] = acc[m][n][j] * alpha;
}

// ---------------- row softmax in place: 65536 rows x 2048 f32 ----------------
__global__ __launch_bounds__(256) void softmax_rows(float* __restrict__ attn) {
    long long row = blockIdx.x;
    float* p = attn + row * 2048;
    int tid = threadIdx.x;
    float4 a = ((const float4*)p)[tid];
    float4 b = ((const float4*)p)[tid + 256];
    float m = fmaxf(fmaxf(fmaxf(a.x, a.y), fmaxf(a.z, a.w)),
                    fmaxf(fmaxf(b.x, b.y), fmaxf(b.z, b.w)));
#pragma unroll
    for (int o = 32; o > 0; o >>= 1) m = fmaxf(m, __shfl_xor(m, o, 64));
    __shared__ float sm[4], ss[4];
    int wid = tid >> 6, lane = tid & 63;
    if (lane == 0) sm[wid] = m;
    __syncthreads();
    m = fmaxf(fmaxf(sm[0], sm[1]), fmaxf(sm[2], sm[3]));
    float e0 = __expf(a.x - m), e1 = __expf(a.y - m), e2 = __expf(a.z - m), e3 = __expf(a.w - m);
    float e4 = __expf(b.x - m), e5 = __expf(b.y - m), e6 = __expf(b.z - m), e7 = __expf(b.w - m);
    float s = ((e0 + e1) + (e2 + e3)) + ((e4 + e5) + (e6 + e7));
#pragma unroll
    for (int o = 32; o > 0; o >>= 1) s += __shfl_xor(s, o, 64);
    if (lane == 0) ss[wid] = s;
    __syncthreads();
    s = (ss[0] + ss[1]) + (ss[2] + ss[3]);
    float inv = 1.0f / s;
    a.x = e0 * inv; a.y = e1 * inv; a.z = e2 * inv; a.w = e3 * inv;
    b.x = e4 * inv; b.y = e5 * inv; b.z = e6 * inv; b.w = e7 * inv;
    ((float4*)p)[tid] = a;
    ((float4*)p)[tid + 256] = b;
}

extern "C" void kernel_launch(void* const* d_in, const int* in_sizes, int n_in,
                              void* d_out, int out_size, void* d_ws, size_t ws_size,
                              hipStream_t stream) {
    const float* x  = (const float*)d_in[0];
    const float* Wq = (const float*)d_in[1];
    const float* Wk = (const float*)d_in[2];
    const float* Wv = (const float*)d_in[3];
    const float* Wo = (const float*)d_in[4];
    float* out = (float*)d_out;
    float* attn = out + (size_t)NSEQ * DMODEL;

    // workspace carve (all 256B aligned)
    char* w = (char*)d_ws;
    auto alloc = [&](size_t bytes) { char* p = w; w += (bytes + 255) & ~(size_t)255; return p; };
    const size_t MD = (size_t)NSEQ * DMODEL;        // 4M
    const size_t MKV = (size_t)NSEQ * NKV * DK;     // 1M
    _Float16* xh   = (_Float16*)alloc(MD * 2);
    _Float16* WqT  = (_Float16*)alloc(MD * 2);
    _Float16* WkT  = (_Float16*)alloc(MKV * 2);
    _Float16* WvT  = (_Float16*)alloc(MKV * 2);
    _Float16* WoT  = (_Float16*)alloc(MD * 2);
    float2*   cs   = (float2*)alloc((size_t)NSEQ * 32 * sizeof(float2));
    float*    Qf   = (float*)alloc(MD * 4);
    float*    Kf   = (float*)alloc(MKV * 4);
    float*    Vf   = (float*)alloc(MKV * 4);
    _Float16* Qh   = (_Float16*)alloc(MD * 2);
    _Float16* Kh   = (_Float16*)alloc(MKV * 2);
    _Float16* Vt   = (_Float16*)alloc(MKV * 2);
    float*    AVf  = Qf;   // reuse (Qf dead after rope_apply)
    _Float16* AVh  = xh;   // reuse (xh dead after V projection)

    // 1. convert x
    cvt_f32_f16<<<2048, 256, 0, stream>>>(x, xh, (int)(MD / 4));
    // 2-5. transpose+convert weights
    transpose_cvt<<<dim3(DMODEL / 32, DMODEL / 32), dim3(32, 8), 0, stream>>>(Wq, WqT, DMODEL, DMODEL);
    transpose_cvt<<<dim3(512 / 32, DMODEL / 32), dim3(32, 8), 0, stream>>>(Wk, WkT, DMODEL, 512);
    transpose_cvt<<<dim3(512 / 32, DMODEL / 32), dim3(32, 8), 0, stream>>>(Wv, WvT, DMODEL, 512);
    transpose_cvt<<<dim3(DMODEL / 32, DMODEL / 32), dim3(32, 8), 0, stream>>>(Wo, WoT, DMODEL, DMODEL);
    // 6. rope table
    rope_table<<<256, 256, 0, stream>>>(cs);
    // 7-9. projections (f32 out)
    gemm_bt<128, 128, 4, 4, false><<<dim3(16, 16, 1), 256, 0, stream>>>(
        xh, WqT, Qf, DMODEL, DMODEL, DMODEL, DMODEL, 0, 0, 1, 0, 1.0f);
    gemm_bt<128, 128, 4, 4, false><<<dim3(4, 16, 1), 256, 0, stream>>>(
        xh, WkT, Kf, DMODEL, DMODEL, DMODEL, 512, 0, 0, 1, 0, 1.0f);
    gemm_bt<128, 128, 4, 4, false><<<dim3(4, 16, 1), 256, 0, stream>>>(
        xh, WvT, Vf, DMODEL, DMODEL, DMODEL, 512, 0, 0, 1, 0, 1.0f);
    // 10-11. RoPE + cvt to f16
    rope_apply<<<(int)(MD / 2 / 256), 256, 0, stream>>>(Qf, cs, Qh, DMODEL);
    rope_apply<<<(int)(MKV / 2 / 256), 256, 0, stream>>>(Kf, cs, Kh, 512);
    // 12. V transpose to [512][2048] f16
    transpose_cvt<<<dim3(512 / 32, NSEQ / 32), dim3(32, 8), 0, stream>>>(Vf, Vt, NSEQ, 512);
    // 13. S = Q K^T * scale  -> attn slab (raw scores)
    gemm_bt<128, 128, 4, 4, false><<<dim3(16, 16, NHEADS), 256, 0, stream>>>(
        Qh, Kh, attn, DK, DMODEL, 512, NSEQ,
        /*az=*/DK, /*bz=*/DK, /*bzdiv=*/4, /*cz=*/(long long)NSEQ * NSEQ, 0.125f);
    // 14. softmax rows in place
    softmax_rows<<<NHEADS * NSEQ, 256, 0, stream>>>(attn);
    // 15. O = P @ V  (A = attn f32, converted inline)
    gemm_bt<128, 64, 4, 2, true><<<dim3(1, 16, NHEADS), 256, 0, stream>>>(
        attn, Vt, AVf, NSEQ, NSEQ, NSEQ, DMODEL,
        /*az=*/NSEQ * NSEQ, /*bz=*/DK * NSEQ, /*bzdiv=*/4, /*cz=*/DK, 1.0f);
    // 16. cvt AV
    cvt_f32_f16<<<2048, 256, 0, stream>>>(AVf, AVh, (int)(MD / 4));
    // 17. out = AV @ Wo
    gemm_bt<128, 128, 4, 4, false><<<dim3(16, 16, 1), 256, 0, stream>>>(
        AVh, WoT, out, DMODEL, DMODEL, DMODEL, DMODEL, 0, 0, 1, 0, 1.0f);
}

// Round 2
// 752.181 us; speedup vs baseline: 1.2007x; 1.2007x over previous
//
#include <hip/hip_runtime.h>

typedef _Float16 f16x8 __attribute__((ext_vector_type(8)));
typedef _Float16 f16x4 __attribute__((ext_vector_type(4)));
typedef float f32x4 __attribute__((ext_vector_type(4)));

#define NSEQ 2048
#define DMODEL 2048
#define NHEADS 32
#define NKV 8
#define DK 64

// ---------------- elementwise f32 -> f16 ----------------
__global__ void cvt_f32_f16(const float* __restrict__ in, _Float16* __restrict__ out, int n4) {
    int i = blockIdx.x * blockDim.x + threadIdx.x;
    int stride = gridDim.x * blockDim.x;
    for (; i < n4; i += stride) {
        float4 v = ((const float4*)in)[i];
        f16x4 h;
        h[0] = (_Float16)v.x; h[1] = (_Float16)v.y;
        h[2] = (_Float16)v.z; h[3] = (_Float16)v.w;
        ((f16x4*)out)[i] = h;
    }
}

// ---------------- transpose + convert: in f32 [R][C] -> out f16 [C][R] ----------------
__global__ __launch_bounds__(256) void transpose_cvt(const float* __restrict__ in,
                                                     _Float16* __restrict__ out,
                                                     int R, int C) {
    __shared__ float tile[32][33];
    int c0 = blockIdx.x * 32, r0 = blockIdx.y * 32;
    int tx = threadIdx.x, ty = threadIdx.y; // (32,8)
#pragma unroll
    for (int i = 0; i < 4; i++) {
        int r = r0 + ty + i * 8;
        tile[ty + i * 8][tx] = in[(long long)r * C + c0 + tx];
    }
    __syncthreads();
#pragma unroll
    for (int i = 0; i < 4; i++) {
        int c = c0 + ty + i * 8;
        out[(long long)c * R + r0 + tx] = (_Float16)tile[tx][ty + i * 8];
    }
}

// ---------------- RoPE cos/sin table ----------------
__global__ void rope_table(float2* __restrict__ cs) {
    int idx = blockIdx.x * blockDim.x + threadIdx.x; // 65536 total
    int n = idx >> 5, j = idx & 31;
    float e = (2.0f * j) / 64.0f;
    float invf = 1.0f / powf(10000.0f, e);
    float ang = (float)n * invf;
    float2 v; v.x = cosf(ang); v.y = sinf(ang);
    cs[idx] = v;
}

// ---------------- RoPE apply + f32->f16 ----------------
__global__ void rope_apply(const float* __restrict__ Qf, const float2* __restrict__ cs,
                           _Float16* __restrict__ Qh, int ncols) {
    int idx = blockIdx.x * blockDim.x + threadIdx.x;
    int halfrow = ncols >> 1;
    int n = idx / halfrow;
    int rem = idx - n * halfrow;
    int h = rem >> 5, j = rem & 31;
    float2 c = cs[n * 32 + j];
    long long base = (long long)n * ncols + h * 64;
    float x1 = Qf[base + j], x2 = Qf[base + j + 32];
    Qh[base + j]      = (_Float16)(x1 * c.x - x2 * c.y);
    Qh[base + j + 32] = (_Float16)(x2 * c.x + x1 * c.y);
}

// ---------------- GEMM: C[M,N] = A[M,K] @ Bt[N,K]^T  (fp16 MFMA, f32 accum) ----------------
template <int BM, int BN, int MF, int NF>
__global__ __launch_bounds__(256) void gemm_bt(const _Float16* __restrict__ Ap,
                                               const _Float16* __restrict__ Bt,
                                               float* __restrict__ C,
                                               int K, int lda, int ldb, int ldc) {
    constexpr int LDP = 56;
    __shared__ __align__(16) _Float16 As[BM][LDP];
    __shared__ __align__(16) _Float16 Bs[BN][LDP];

    const int tid = threadIdx.x;
    const int lane = tid & 63, wid = tid >> 6;
    constexpr int WC = BN / (NF * 16);
    const int wr = wid / WC, wc = wid % WC;
    const int wm = wr * MF * 16, wn = wc * NF * 16;
    const int am = lane & 15;
    const int k0 = (lane >> 4) * 8;

    f32x4 acc[MF][NF] = {};

    const long long a_row0 = (long long)blockIdx.y * BM * lda;
    const long long b_row0 = (long long)blockIdx.x * BN * ldb;

    for (int kt = 0; kt < K; kt += 32) {
        const _Float16* A = Ap + a_row0 + kt;
        for (int c = tid; c < BM * 4; c += 256) {
            int r = c >> 2, s = c & 3;
            *(f16x8*)&As[r][s * 8] = *(const f16x8*)(A + (long long)r * lda + s * 8);
        }
        const _Float16* B = Bt + b_row0 + kt;
        for (int c = tid; c < BN * 4; c += 256) {
            int r = c >> 2, s = c & 3;
            *(f16x8*)&Bs[r][s * 8] = *(const f16x8*)(B + (long long)r * ldb + s * 8);
        }
        __syncthreads();

        f16x8 af[MF], bf[NF];
#pragma unroll
        for (int m = 0; m < MF; m++) af[m] = *(const f16x8*)&As[wm + m * 16 + am][k0];
#pragma unroll
        for (int n = 0; n < NF; n++) bf[n] = *(const f16x8*)&Bs[wn + n * 16 + am][k0];
#pragma unroll
        for (int m = 0; m < MF; m++)
#pragma unroll
            for (int n = 0; n < NF; n++)
                acc[m][n] = __builtin_amdgcn_mfma_f32_16x16x32_f16(af[m], bf[n], acc[m][n], 0, 0, 0);
        __syncthreads();
    }

    const int rb = blockIdx.y * BM + wm + (lane >> 4) * 4;
    const int cb = blockIdx.x * BN + wn + am;
#pragma unroll
    for (int m = 0; m < MF; m++)
#pragma unroll
        for (int n = 0; n < NF; n++)
#pragma unroll
            for (int j = 0; j < 4; j++)
                C[(long long)(rb + m * 16 + j) * ldc + cb + n * 16] = acc[m][n][j];
}

// ---------------- fused attention: S, softmax, attn-write, PV ----------------
__device__ __forceinline__ float wmax16(float v) {
#pragma unroll
    for (int o = 1; o < 16; o <<= 1) v = fmaxf(v, __shfl_xor(v, o, 64));
    return v;
}
__device__ __forceinline__ float wsum16(float v) {
#pragma unroll
    for (int o = 1; o < 16; o <<= 1) v += __shfl_xor(v, o, 64);
    return v;
}
#define SWZB(row, byte) ((byte) ^ (((row) & 7) << 4))

__global__ __launch_bounds__(256) void fused_attn(
    const _Float16* __restrict__ Qh,   // [2048][2048] (n, h*64+d), roped
    const _Float16* __restrict__ Kh,   // [2048][512]  (n, kvh*64+d), roped
    const _Float16* __restrict__ Vt,   // [512][2048]  (kvh*64+d, n)
    float* __restrict__ attn,          // [32][2048][2048]
    _Float16* __restrict__ AVh)        // [2048][2048] (n, h*64+d)
{
    __shared__ __align__(16) _Float16 P16[16 * 1024]; // 32 KB, swizzled
    __shared__ float wm[4][16], ws[4][16], s_max[16], s_inv[16];

    const int h = blockIdx.y, rbk = blockIdx.x;
    const int kvh = h >> 2;
    const int tid = threadIdx.x, lane = tid & 63, wid = tid >> 6;
    const int g = lane >> 4, c = lane & 15;

    // Q fragments (rows rbk*16 + c), k = 0..63
    const long long qrow = (long long)(rbk * 16 + c) * DMODEL + h * 64;
    const f16x8 qa0 = *(const f16x8*)(Qh + qrow + g * 8);
    const f16x8 qa1 = *(const f16x8*)(Qh + qrow + 32 + g * 8);
    const int kb_off = kvh * 64;

    // ---- phase 1: online max + sum (no S storage) ----
    float m[4] = {-1e30f, -1e30f, -1e30f, -1e30f};
    float ps[4] = {0.f, 0.f, 0.f, 0.f};
#pragma unroll 2
    for (int i = 0; i < 32; i++) {
        int cb = wid + 4 * i;
        const _Float16* kp = Kh + (long long)(cb * 16 + c) * 512 + kb_off;
        f16x8 kb0 = *(const f16x8*)(kp + g * 8);
        f16x8 kb1 = *(const f16x8*)(kp + 32 + g * 8);
        f32x4 acc = {0.f, 0.f, 0.f, 0.f};
        acc = __builtin_amdgcn_mfma_f32_16x16x32_f16(qa0, kb0, acc, 0, 0, 0);
        acc = __builtin_amdgcn_mfma_f32_16x16x32_f16(qa1, kb1, acc, 0, 0, 0);
#pragma unroll
        for (int j = 0; j < 4; j++) {
            float s = acc[j] * 0.125f;
            float bm = wmax16(s);
            float mn = fmaxf(m[j], bm);
            ps[j] = ps[j] * __expf(m[j] - mn) + __expf(s - mn);
            m[j] = mn;
        }
    }
#pragma unroll
    for (int j = 0; j < 4; j++) ps[j] = wsum16(ps[j]);
    if (c == 0) {
#pragma unroll
        for (int j = 0; j < 4; j++) { wm[wid][4 * g + j] = m[j]; ws[wid][4 * g + j] = ps[j]; }
    }
    __syncthreads();
    if (tid < 16) {
        float M = fmaxf(fmaxf(wm[0][tid], wm[1][tid]), fmaxf(wm[2][tid], wm[3][tid]));
        float S = ws[0][tid] * __expf(wm[0][tid] - M) + ws[1][tid] * __expf(wm[1][tid] - M) +
                  ws[2][tid] * __expf(wm[2][tid] - M) + ws[3][tid] * __expf(wm[3][tid] - M);
        s_max[tid] = M;
        s_inv[tid] = 1.0f / S;
    }
    __syncthreads();

    float Mr[4];
#pragma unroll
    for (int j = 0; j < 4; j++) Mr[j] = s_max[4 * g + j];

    // ---- phases 2/3: two 1024-col halves: recompute S -> e(fp16, LDS) -> attn write + PV ----
    f32x4 opv = {0.f, 0.f, 0.f, 0.f};
    for (int half = 0; half < 2; half++) {
#pragma unroll 2
        for (int i = 0; i < 16; i++) {
            int cbl = wid + 4 * i;            // 0..63 local col-block
            int cb = half * 64 + cbl;
            const _Float16* kp = Kh + (long long)(cb * 16 + c) * 512 + kb_off;
            f16x8 kb0 = *(const f16x8*)(kp + g * 8);
            f16x8 kb1 = *(const f16x8*)(kp + 32 + g * 8);
            f32x4 acc = {0.f, 0.f, 0.f, 0.f};
            acc = __builtin_amdgcn_mfma_f32_16x16x32_f16(qa0, kb0, acc, 0, 0, 0);
            acc = __builtin_amdgcn_mfma_f32_16x16x32_f16(qa1, kb1, acc, 0, 0, 0);
            int col = cbl * 16 + c;
#pragma unroll
            for (int j = 0; j < 4; j++) {
                float e = __expf(acc[j] * 0.125f - Mr[j]);
                int row = 4 * g + j;
                int byte = SWZB(row, row * 2048 + col * 2);
                *(_Float16*)((char*)P16 + byte) = (_Float16)e;
            }
        }
        __syncthreads();

        // coalesced attn write for this half
        {
            int t = tid & 127, rh = tid >> 7;
#pragma unroll
            for (int r2 = 0; r2 < 8; r2++) {
                int r = r2 * 2 + rh;
                int byte = SWZB(r, r * 2048 + t * 16);
                f16x8 ev = *(const f16x8*)((char*)P16 + byte);
                float inv = s_inv[r];
                float4 o0, o1;
                o0.x = (float)ev[0] * inv; o0.y = (float)ev[1] * inv;
                o0.z = (float)ev[2] * inv; o0.w = (float)ev[3] * inv;
                o1.x = (float)ev[4] * inv; o1.y = (float)ev[5] * inv;
                o1.z = (float)ev[6] * inv; o1.w = (float)ev[7] * inv;
                float* dst = attn + ((long long)h * NSEQ + rbk * 16 + r) * NSEQ + half * 1024 + t * 8;
                *(float4*)dst = o0;
                *(float4*)(dst + 4) = o1;
            }
        }

        // PV for this half: wave wid owns d-cols wid*16..+15
        {
            const _Float16* vrow = Vt + (long long)(kvh * 64 + wid * 16 + c) * NSEQ + half * 1024;
#pragma unroll 4
            for (int kk = 0; kk < 1024; kk += 32) {
                int abyte = SWZB(c, c * 2048 + (kk + g * 8) * 2);
                f16x8 pa = *(const f16x8*)((char*)P16 + abyte);
                f16x8 vb = *(const f16x8*)(vrow + kk + g * 8);
                opv = __builtin_amdgcn_mfma_f32_16x16x32_f16(pa, vb, opv, 0, 0, 0);
            }
        }
        __syncthreads();
    }

    // epilogue: AV (fp16) for out-projection
#pragma unroll
    for (int j = 0; j < 4; j++) {
        int row = 4 * g + j;
        float val = opv[j] * s_inv[row];
        AVh[(long long)(rbk * 16 + row) * DMODEL + h * 64 + wid * 16 + c] = (_Float16)val;
    }
}

extern "C" void kernel_launch(void* const* d_in, const int* in_sizes, int n_in,
                              void* d_out, int out_size, void* d_ws, size_t ws_size,
                              hipStream_t stream) {
    const float* x  = (const float*)d_in[0];
    const float* Wq = (const float*)d_in[1];
    const float* Wk = (const float*)d_in[2];
    const float* Wv = (const float*)d_in[3];
    const float* Wo = (const float*)d_in[4];
    float* out = (float*)d_out;
    float* attn = out + (size_t)NSEQ * DMODEL;

    char* w = (char*)d_ws;
    auto alloc = [&](size_t bytes) { char* p = w; w += (bytes + 255) & ~(size_t)255; return p; };
    const size_t MD = (size_t)NSEQ * DMODEL;        // 4M
    const size_t MKV = (size_t)NSEQ * NKV * DK;     // 1M
    _Float16* xh   = (_Float16*)alloc(MD * 2);
    _Float16* WqT  = (_Float16*)alloc(MD * 2);
    _Float16* WkT  = (_Float16*)alloc(MKV * 2);
    _Float16* WvT  = (_Float16*)alloc(MKV * 2);
    _Float16* WoT  = (_Float16*)alloc(MD * 2);
    float2*   cs   = (float2*)alloc((size_t)NSEQ * 32 * sizeof(float2));
    float*    Qf   = (float*)alloc(MD * 4);
    float*    Kf   = (float*)alloc(MKV * 4);
    float*    Vf   = (float*)alloc(MKV * 4);
    _Float16* Qh   = (_Float16*)alloc(MD * 2);
    _Float16* Kh   = (_Float16*)alloc(MKV * 2);
    _Float16* Vt   = (_Float16*)alloc(MKV * 2);
    _Float16* AVh  = xh;   // reuse (xh dead after projections)

    cvt_f32_f16<<<2048, 256, 0, stream>>>(x, xh, (int)(MD / 4));
    transpose_cvt<<<dim3(DMODEL / 32, DMODEL / 32), dim3(32, 8), 0, stream>>>(Wq, WqT, DMODEL, DMODEL);
    transpose_cvt<<<dim3(512 / 32, DMODEL / 32), dim3(32, 8), 0, stream>>>(Wk, WkT, DMODEL, 512);
    transpose_cvt<<<dim3(512 / 32, DMODEL / 32), dim3(32, 8), 0, stream>>>(Wv, WvT, DMODEL, 512);
    transpose_cvt<<<dim3(DMODEL / 32, DMODEL / 32), dim3(32, 8), 0, stream>>>(Wo, WoT, DMODEL, DMODEL);
    rope_table<<<256, 256, 0, stream>>>(cs);

    gemm_bt<128, 128, 4, 4><<<dim3(16, 16), 256, 0, stream>>>(xh, WqT, Qf, DMODEL, DMODEL, DMODEL, DMODEL);
    gemm_bt<128, 128, 4, 4><<<dim3(4, 16), 256, 0, stream>>>(xh, WkT, Kf, DMODEL, DMODEL, DMODEL, 512);
    gemm_bt<128, 128, 4, 4><<<dim3(4, 16), 256, 0, stream>>>(xh, WvT, Vf, DMODEL, DMODEL, DMODEL, 512);

    rope_apply<<<(int)(MD / 2 / 256), 256, 0, stream>>>(Qf, cs, Qh, DMODEL);
    rope_apply<<<(int)(MKV / 2 / 256), 256, 0, stream>>>(Kf, cs, Kh, 512);
    transpose_cvt<<<dim3(512 / 32, NSEQ / 32), dim3(32, 8), 0, stream>>>(Vf, Vt, NSEQ, 512);

    fused_attn<<<dim3(NSEQ / 16, NHEADS), 256, 0, stream>>>(Qh, Kh, Vt, attn, AVh);

    gemm_bt<128, 128, 4, 4><<<dim3(16, 16), 256, 0, stream>>>(AVh, WoT, out, DMODEL, DMODEL, DMODEL, DMODEL);
}